// Round 10
// baseline (1641.472 us; speedup 1.0000x reference)
//
#include <hip/hip_runtime.h>
#include <hip/hip_fp16.h>

typedef _Float16 f16;
typedef _Float16 f16x8 __attribute__((ext_vector_type(8)));
typedef _Float16 f16x4 __attribute__((ext_vector_type(4)));
typedef float f32x4v __attribute__((ext_vector_type(4)));
typedef unsigned long long u64;

#define S_LEN 1024
#define NS 512
#define NV 32000
#define NW 4          // scan workers (CUs); each owns 128 n-columns
#define SENT 0x7C007C007C007C00ULL   // 4x f16 +inf: unreachable for tanh output
#define FUSED_LDS 98304              // >80KB -> exactly 1 block/CU
#define TPB 768                      // 8 compute waves + 4 gather waves

#define MFMA16(a, b, c) __builtin_amdgcn_mfma_f32_16x16x32_f16((a), (b), (c), 0, 0, 0)

// ---------------------------------------------------------------------------
// ws layout:
//   u16   : [1024][512][4] f16  at 0      (4 MB)   u[s][n][b]  (batch-packed)
//   X     : u64[1024][512]      at 4 MB   (4 MB)   state record + exchange
//   bT16  : [512][512]     f16  at 8 MB   (512 KB)
// ---------------------------------------------------------------------------

// transpose b -> f16, and refill X with sentinel (every launch; graph-safe)
__global__ __launch_bounds__(256) void transpose512_f16_kernel(
        const float* __restrict__ src, f16* __restrict__ dstT,
        u64* __restrict__ X) {
    int idx = blockIdx.x * 256 + threadIdx.x;   // 0..262143
    X[idx] = SENT;
    X[idx + 262144] = SENT;
    int r = idx >> 9;
    int c = idx & 511;
    dstT[c * 512 + r] = (f16)src[idx];
}

// ---------------------------------------------------------------------------
// embed + input projection: u[m][n] = sum_e emb[x[m]][e] * b[e][n], m = s*4+b
// ---------------------------------------------------------------------------
__global__ __launch_bounds__(256) void embu_kernel(
        const int* __restrict__ x, const float* __restrict__ emb,
        const f16* __restrict__ bT, f16* __restrict__ u16) {
    __shared__ f16 embA[64 * 40];
    __shared__ f16 Bt[512 * 40];
    __shared__ int xi[64];

    int t = threadIdx.x;
    int wg = blockIdx.x;
    if (t < 64) {
        int m = wg * 64 + t;
        int bb = m & 3, ss = m >> 2;
        xi[t] = x[bb * S_LEN + ss];
    }
    __syncthreads();

    int wv = t >> 6, l = t & 63, lr = l & 15, lg = l >> 4;

    f32x4v acc[32];
#pragma unroll
    for (int i = 0; i < 32; i++) acc[i] = (f32x4v){0.f, 0.f, 0.f, 0.f};

    for (int kc = 0; kc < 512; kc += 32) {
        __syncthreads();
        {
            int tk = t >> 2, c0 = (t & 3) * 8;
            const float* src = emb + (size_t)xi[tk] * NS + kc + c0;
            float4 v0 = *(const float4*)src;
            float4 v1 = *(const float4*)(src + 4);
            f16x8 h;
            h[0] = (f16)v0.x; h[1] = (f16)v0.y; h[2] = (f16)v0.z; h[3] = (f16)v0.w;
            h[4] = (f16)v1.x; h[5] = (f16)v1.y; h[6] = (f16)v1.z; h[7] = (f16)v1.w;
            *(f16x8*)&embA[tk * 40 + c0] = h;
        }
        {
            int c0 = (t & 3) * 8;
            int n0 = t >> 2;
#pragma unroll
            for (int rr = 0; rr < 8; rr++) {
                int n = rr * 64 + n0;
                f16x8 v = *(const f16x8*)&bT[n * 512 + kc + c0];
                *(f16x8*)&Bt[n * 40 + c0] = v;
            }
        }
        __syncthreads();

        f16x8 af = *(const f16x8*)&embA[(wv * 16 + lr) * 40 + 8 * lg];
#pragma unroll
        for (int vt = 0; vt < 32; vt++) {
            f16x8 bf = *(const f16x8*)&Bt[(vt * 16 + lr) * 40 + 8 * lg];
            acc[vt] = MFMA16(af, bf, acc[vt]);
        }
    }

    int m0 = wg * 64 + wv * 16 + 4 * lg;
    int ss = m0 >> 2;
#pragma unroll
    for (int vt = 0; vt < 32; vt++) {
        int n = vt * 16 + lr;
        f16x4 h;
#pragma unroll
        for (int i = 0; i < 4; i++) h[i] = (f16)acc[vt][i];
        *(f16x4*)&u16[((size_t)ss * NS + n) * 4] = h;
    }
}

// ---------------------------------------------------------------------------
// FUSED scan + readout.
//   blocks 0..3    : scan, barrier-free LDS-flag pipeline, tri-buffered state.
//                    waves 0-7 compute 16 cols each; waves 8-11 gather 3
//                    remote 32-col slices each via X data-poll.
//   blocks 4..4003 : readout tiles (canary gate + per-element sentinel poll)
// ---------------------------------------------------------------------------
__global__ __launch_bounds__(TPB) void fused_kernel(
        const float* __restrict__ a, const f16* __restrict__ u16,
        const float* __restrict__ cw, const float* __restrict__ cb,
        u64* __restrict__ X, float* __restrict__ out) {
    extern __shared__ char smem[];
    int t = threadIdx.x;
    int bid = blockIdx.x;
    int w = t >> 6, l = t & 63, lr = l & 15, lg = l >> 4;

    if (bid < NW) {
        // ================= scan =================
        f16* Sb = (f16*)smem;                      // [3][4][544] f16
        int* flg = (int*)(smem + 3 * 4 * 544 * 2); // [16]: 0-7 halves, 8-11 gw
        int r = bid;

        for (int i = t; i < 3 * 4 * 544; i += TPB) Sb[i] = (f16)0.f;
        if (t < 16) flg[t] = 0;
        __syncthreads();

        if (w < 8) {
            // ---------- compute wave: 16 output cols ----------
            int col = r * 128 + w * 16 + lr;

            // A fragments in PROCESSING order (compile-time indices, rule #20)
            f16x8 afr_own[4], afr_rem[12];
#pragma unroll
            for (int q = 0; q < 4; q++) {
                int k = 4 * r + q;
                f16x8 h;
#pragma unroll
                for (int j = 0; j < 8; j++)
                    h[j] = (f16)a[(size_t)(k * 32 + 8 * lg + j) * NS + col];
                afr_own[q] = h;
            }
#pragma unroll
            for (int idx = 0; idx < 12; idx++) {
                int k = idx + (idx >= 4 * r ? 4 : 0);
                f16x8 h;
#pragma unroll
                for (int j = 0; j < 8; j++)
                    h[j] = (f16)a[(size_t)(k * 32 + 8 * lg + j) * NS + col];
                afr_rem[idx] = h;
            }

            f16x4 upf = *(const f16x4*)&u16[(size_t)col * 4];
            int cs = 0;

#pragma unroll 1
            for (int s = 0; s < S_LEN; s++) {
                int ns = (cs == 2) ? 0 : cs + 1;

                f32x4v acc;
                acc[0] = (float)upf[0]; acc[1] = (float)upf[1];
                acc[2] = (float)upf[2]; acc[3] = (float)upf[3];
                {
                    int sn = (s + 1 < S_LEN) ? s + 1 : S_LEN - 1;
                    upf = *(const f16x4*)&u16[((size_t)sn * NS + col) * 4];
                }

                const char* sbc = (const char*)Sb + cs * 4352 +
                                  (lr & 3) * 1088 + lg * 16;

                // own-CU slices (available earliest: written end of prev step)
#pragma unroll
                for (int q = 0; q < 4; q++) {
                    int k = 4 * r + q;
                    if (l == 0) {
                        while (__hip_atomic_load(&flg[2 * q], __ATOMIC_RELAXED,
                                   __HIP_MEMORY_SCOPE_WORKGROUP) < s ||
                               __hip_atomic_load(&flg[2 * q + 1], __ATOMIC_RELAXED,
                                   __HIP_MEMORY_SCOPE_WORKGROUP) < s) {}
                    }
                    __builtin_amdgcn_sched_barrier(0);
                    f16x8 sf = *(const f16x8*)(sbc + k * 64);
                    acc = MFMA16(sf, afr_own[q], acc);
                }
                // remote slices, gated per gather wave
#pragma unroll
                for (int g = 0; g < 4; g++) {
                    if (l == 0) {
                        while (__hip_atomic_load(&flg[8 + g], __ATOMIC_RELAXED,
                                   __HIP_MEMORY_SCOPE_WORKGROUP) < s) {}
                    }
                    __builtin_amdgcn_sched_barrier(0);
#pragma unroll
                    for (int i = 0; i < 3; i++) {
                        int idx = g * 3 + i;
                        int k = idx + (idx >= 4 * r ? 4 : 0);
                        f16x8 sf = *(const f16x8*)(sbc + k * 64);
                        acc = MFMA16(sf, afr_rem[idx], acc);
                    }
                }

                // tanh + publish X (fire-and-forget)
                union { u64 u; f16 h[4]; } pk;
                if (lg == 0) {
#pragma unroll
                    for (int i = 0; i < 4; i++) {
                        float y = acc[i];
                        float e = __expf(2.0f * y);
                        float rc = __builtin_amdgcn_rcpf(e + 1.0f);
                        y = __builtin_fmaf(-2.0f, rc, 1.0f);   // tanh
                        pk.h[i] = (f16)y;
                    }
                    __hip_atomic_store(&X[(size_t)s * NS + col], pk.u,
                                       __ATOMIC_RELAXED, __HIP_MEMORY_SCOPE_AGENT);
                }
                if (s == S_LEN - 1) break;

                if (lg == 0) {
                    f16* sbn = Sb + ns * 2176;
#pragma unroll
                    for (int i = 0; i < 4; i++)
                        sbn[i * 544 + col] = pk.h[i];
                }
                asm volatile("s_waitcnt lgkmcnt(0)" ::: "memory");
                __builtin_amdgcn_sched_barrier(0);
                if (l == 0)
                    __hip_atomic_store(&flg[w], s + 1, __ATOMIC_RELAXED,
                                       __HIP_MEMORY_SCOPE_WORKGROUP);
                cs = ns;
            }
        } else {
            // ---------- gather wave: 3 remote 32-col slices ----------
            int gw = w - 8;
            int i0 = gw * 3 + (l >> 5);
            int k0 = i0 + (i0 >= 4 * r ? 4 : 0);
            int colA = k0 * 32 + (l & 31);
            int i2 = gw * 3 + 2;
            int k2 = i2 + (i2 >= 4 * r ? 4 : 0);
            int colB = (l < 32) ? (k2 * 32 + l) : colA;

            int nb = 1;   // buffer holding state g+1
#pragma unroll 1
            for (int g = 0; g < S_LEN - 1; g++) {
                const u64* pA = &X[(size_t)g * NS + colA];
                const u64* pB = &X[(size_t)g * NS + colB];
                u64 vA = SENT;
                u64 vB = (l < 32) ? SENT : 0ULL;
                while (vA == SENT || vB == SENT) {
                    if (vA == SENT)
                        vA = __hip_atomic_load(pA, __ATOMIC_RELAXED,
                                               __HIP_MEMORY_SCOPE_AGENT);
                    if (vB == SENT)
                        vB = __hip_atomic_load(pB, __ATOMIC_RELAXED,
                                               __HIP_MEMORY_SCOPE_AGENT);
                }
                __builtin_amdgcn_sched_barrier(0);
                f16* sbn = Sb + nb * 2176;
                union { u64 u; f16 h[4]; } pa;
                pa.u = vA;
#pragma unroll
                for (int i = 0; i < 4; i++) sbn[i * 544 + colA] = pa.h[i];
                if (l < 32) {
                    union { u64 u; f16 h[4]; } pb;
                    pb.u = vB;
#pragma unroll
                    for (int i = 0; i < 4; i++) sbn[i * 544 + colB] = pb.h[i];
                }
                asm volatile("s_waitcnt lgkmcnt(0)" ::: "memory");
                __builtin_amdgcn_sched_barrier(0);
                if (l == 0)
                    __hip_atomic_store(&flg[8 + gw], g + 1, __ATOMIC_RELAXED,
                                       __HIP_MEMORY_SCOPE_WORKGROUP);
                nb = (nb == 2) ? 0 : nb + 1;
            }
        }
        return;
    }

    // ================= readout =================
    f16* Ast = (f16*)smem;                 // [256][72]
    f16* Bw = (f16*)(smem + 256 * 72 * 2); // [128][72]

    int idx = bid - NW;
    int bm = idx / 250;      // bm-major: early blocks handle early s
    int bn = idx % 250;
    int s0 = bm * 64;

    if (t == 0) {
        int sc = (bm == 15) ? (S_LEN - 1) : (s0 + 64);
        while (__hip_atomic_load(&X[(size_t)sc * NS], __ATOMIC_RELAXED,
                                 __HIP_MEMORY_SCOPE_AGENT) == SENT)
            __builtin_amdgcn_s_sleep(16);
    }
    __syncthreads();

    int wr = w >> 1, wc = w & 1;

    f32x4v acc[4][4];
#pragma unroll
    for (int i = 0; i < 4; i++)
#pragma unroll
        for (int j = 0; j < 4; j++) acc[i][j] = (f32x4v){0.f, 0.f, 0.f, 0.f};

    for (int kc = 0; kc < 512; kc += 64) {
        __syncthreads();
        if (t < 512) {
            // stage A from X: 64 s x 64 cols of u64; per-element sentinel poll
            {
                int srel = t >> 3;
                int ck = (t & 7) * 8;
                const u64* xs = &X[(size_t)(s0 + srel) * NS + kc + ck];
                u64 v[8];
#pragma unroll
                for (int j = 0; j < 8; j++)
                    v[j] = __hip_atomic_load(&xs[j], __ATOMIC_RELAXED,
                                             __HIP_MEMORY_SCOPE_AGENT);
#pragma unroll
                for (int j = 0; j < 8; j++)
                    while (v[j] == SENT)
                        v[j] = __hip_atomic_load(&xs[j], __ATOMIC_RELAXED,
                                                 __HIP_MEMORY_SCOPE_AGENT);
#pragma unroll
                for (int j = 0; j < 8; j++) {
                    union { u64 u; f16 h[4]; } pk;
                    pk.u = v[j];
#pragma unroll
                    for (int b = 0; b < 4; b++)
                        Ast[(srel * 4 + b) * 72 + ck + j] = pk.h[b];
                }
            }
#pragma unroll
            for (int q = 0; q < 4; q++) {
                int i2 = q * 512 + t;
                int row = i2 >> 4;
                int c0 = (i2 & 15) * 4;
                float4 v = *(const float4*)&cw[(size_t)(bn * 128 + row) * NS + kc + c0];
                f16x4 h;
                h[0] = (f16)v.x; h[1] = (f16)v.y; h[2] = (f16)v.z; h[3] = (f16)v.w;
                *(f16x4*)&Bw[row * 72 + c0] = h;
            }
        }
        __syncthreads();

        if (w < 8) {
#pragma unroll
            for (int ks = 0; ks < 2; ks++) {
                f16x8 af[4], bf[4];
#pragma unroll
                for (int mt = 0; mt < 4; mt++)
                    af[mt] = *(const f16x8*)&Ast[(wr * 64 + mt * 16 + lr) * 72 +
                                                 ks * 32 + 8 * lg];
#pragma unroll
                for (int vt = 0; vt < 4; vt++)
                    bf[vt] = *(const f16x8*)&Bw[(wc * 64 + vt * 16 + lr) * 72 +
                                                ks * 32 + 8 * lg];
#pragma unroll
                for (int mt = 0; mt < 4; mt++)
#pragma unroll
                    for (int vt = 0; vt < 4; vt++)
                        acc[mt][vt] = MFMA16(af[mt], bf[vt], acc[mt][vt]);
            }
        }
    }

    if (w < 8) {
        float bias[4];
#pragma unroll
        for (int vt = 0; vt < 4; vt++)
            bias[vt] = cb[bn * 128 + wc * 64 + vt * 16 + lr];

#pragma unroll
        for (int mt = 0; mt < 4; mt++) {
#pragma unroll
            for (int i = 0; i < 4; i++) {
                int m = bm * 256 + wr * 64 + mt * 16 + 4 * lg + i;
                int bb = m & 3, ss = m >> 2;
                float* orow = out + (size_t)(bb * S_LEN + ss) * NV +
                              bn * 128 + wc * 64;
#pragma unroll
                for (int vt = 0; vt < 4; vt++)
                    orow[vt * 16 + lr] = acc[mt][vt][i] + bias[vt];
            }
        }
    }
}

// ---------------------------------------------------------------------------
extern "C" void kernel_launch(void* const* d_in, const int* in_sizes, int n_in,
                              void* d_out, int out_size, void* d_ws, size_t ws_size,
                              hipStream_t stream) {
    (void)in_sizes; (void)n_in; (void)out_size; (void)ws_size;

    const int*   x   = (const int*)d_in[0];
    const float* emb = (const float*)d_in[1];
    const float* a   = (const float*)d_in[2];
    const float* bm  = (const float*)d_in[3];
    const float* cw  = (const float*)d_in[4];
    const float* cb  = (const float*)d_in[5];
    float* out = (float*)d_out;

    char* ws = (char*)d_ws;
    f16* u16 = (f16*)(ws);
    u64* X   = (u64*)(ws + (4u << 20));
    f16* bT16 = (f16*)(ws + (8u << 20));

    hipFuncSetAttribute(reinterpret_cast<const void*>(fused_kernel),
                        hipFuncAttributeMaxDynamicSharedMemorySize,
                        FUSED_LDS);

    transpose512_f16_kernel<<<1024, 256, 0, stream>>>(bm, bT16, X);
    embu_kernel<<<64, 256, 0, stream>>>(x, emb, bT16, u16);
    fused_kernel<<<NW + 16 * 250, TPB, FUSED_LDS, stream>>>(
        a, u16, cw, cb, X, out);
}

// Round 11
// 1324.527 us; speedup vs baseline: 1.2393x; 1.2393x over previous
//
#include <hip/hip_runtime.h>
#include <hip/hip_fp16.h>

typedef _Float16 f16;
typedef _Float16 f16x8 __attribute__((ext_vector_type(8)));
typedef _Float16 f16x4 __attribute__((ext_vector_type(4)));
typedef float f32x4v __attribute__((ext_vector_type(4)));
typedef unsigned long long u64;

#define S_LEN 1024
#define NS 512
#define NV 32000
#define NW 4          // scan workers (CUs); each owns 128 n-columns
#define SENT 0x7C007C007C007C00ULL   // 4x f16 +inf: unreachable for tanh output
#define FUSED_LDS 98304              // >80KB -> exactly 1 block/CU

#define MFMA16(a, b, c) __builtin_amdgcn_mfma_f32_16x16x32_f16((a), (b), (c), 0, 0, 0)

// ---------------------------------------------------------------------------
// ws layout:
//   u16   : [1024][512][4] f16  at 0      (4 MB)   u[s][n][b]  (batch-packed)
//   X     : u64[1024][512]      at 4 MB   (4 MB)   state record + exchange
//   bT16  : [512][512]     f16  at 8 MB   (512 KB)
// ---------------------------------------------------------------------------

// transpose b -> f16, and refill X with sentinel (every launch; graph-safe)
__global__ __launch_bounds__(256) void transpose512_f16_kernel(
        const float* __restrict__ src, f16* __restrict__ dstT,
        u64* __restrict__ X) {
    int idx = blockIdx.x * 256 + threadIdx.x;   // 0..262143
    X[idx] = SENT;
    X[idx + 262144] = SENT;
    int r = idx >> 9;
    int c = idx & 511;
    dstT[c * 512 + r] = (f16)src[idx];
}

// ---------------------------------------------------------------------------
// embed + input projection: u[m][n] = sum_e emb[x[m]][e] * b[e][n], m = s*4+b
// ---------------------------------------------------------------------------
__global__ __launch_bounds__(256) void embu_kernel(
        const int* __restrict__ x, const float* __restrict__ emb,
        const f16* __restrict__ bT, f16* __restrict__ u16) {
    __shared__ f16 embA[64 * 40];
    __shared__ f16 Bt[512 * 40];
    __shared__ int xi[64];

    int t = threadIdx.x;
    int wg = blockIdx.x;
    if (t < 64) {
        int m = wg * 64 + t;
        int bb = m & 3, ss = m >> 2;
        xi[t] = x[bb * S_LEN + ss];
    }
    __syncthreads();

    int wv = t >> 6, l = t & 63, lr = l & 15, lg = l >> 4;

    f32x4v acc[32];
#pragma unroll
    for (int i = 0; i < 32; i++) acc[i] = (f32x4v){0.f, 0.f, 0.f, 0.f};

    for (int kc = 0; kc < 512; kc += 32) {
        __syncthreads();
        {
            int tk = t >> 2, c0 = (t & 3) * 8;
            const float* src = emb + (size_t)xi[tk] * NS + kc + c0;
            float4 v0 = *(const float4*)src;
            float4 v1 = *(const float4*)(src + 4);
            f16x8 h;
            h[0] = (f16)v0.x; h[1] = (f16)v0.y; h[2] = (f16)v0.z; h[3] = (f16)v0.w;
            h[4] = (f16)v1.x; h[5] = (f16)v1.y; h[6] = (f16)v1.z; h[7] = (f16)v1.w;
            *(f16x8*)&embA[tk * 40 + c0] = h;
        }
        {
            int c0 = (t & 3) * 8;
            int n0 = t >> 2;
#pragma unroll
            for (int rr = 0; rr < 8; rr++) {
                int n = rr * 64 + n0;
                f16x8 v = *(const f16x8*)&bT[n * 512 + kc + c0];
                *(f16x8*)&Bt[n * 40 + c0] = v;
            }
        }
        __syncthreads();

        f16x8 af = *(const f16x8*)&embA[(wv * 16 + lr) * 40 + 8 * lg];
#pragma unroll
        for (int vt = 0; vt < 32; vt++) {
            f16x8 bf = *(const f16x8*)&Bt[(vt * 16 + lr) * 40 + 8 * lg];
            acc[vt] = MFMA16(af, bf, acc[vt]);
        }
    }

    int m0 = wg * 64 + wv * 16 + 4 * lg;
    int ss = m0 >> 2;
#pragma unroll
    for (int vt = 0; vt < 32; vt++) {
        int n = vt * 16 + lr;
        f16x4 h;
#pragma unroll
        for (int i = 0; i < 4; i++) h[i] = (f16)acc[vt][i];
        *(f16x4*)&u16[((size_t)ss * NS + n) * 4] = h;
    }
}

// ---------------------------------------------------------------------------
// FUSED scan + readout (R7 structure).
//   blocks 0..3     : scan (4 CUs, col-partitioned, data-poll exchange via X)
//   blocks 4..4003  : readout tiles; canary gate; A staged from X with plain
//                     (L2-cacheable) loads + agent-scope fallback on SENT;
//                     register-transposed b128 LDS writes.
// 96 KB dynamic LDS -> 1 block/CU.
// ---------------------------------------------------------------------------
__global__ __launch_bounds__(512) void fused_kernel(
        const float* __restrict__ a, const f16* __restrict__ u16,
        const float* __restrict__ cw, const float* __restrict__ cb,
        u64* __restrict__ X, float* __restrict__ out) {
    extern __shared__ char smem[];
    int t = threadIdx.x;
    int bid = blockIdx.x;
    int w = t >> 6, l = t & 63, lr = l & 15, lg = l >> 4;

    if (bid < NW) {
        // ================= scan =================
        f16* Sb = (f16*)smem;               // [2][4][544] f16
        int r = bid;
        int col = r * 128 + w * 16 + lr;

        int gcol = -1;
        if (w < 6) {
            int cwk = w + (w >= 2 * r ? 2 : 0);   // skip own chunks {2r,2r+1}
            gcol = cwk * 64 + l;
        }

        for (int i = t; i < 2 * 4 * 544; i += 512) Sb[i] = (f16)0.f;

        // stationary A fragments (64 VGPR/lane)
        f16x8 afr[16];
#pragma unroll
        for (int ks = 0; ks < 16; ks++) {
            f16x8 h;
#pragma unroll
            for (int j = 0; j < 8; j++)
                h[j] = (f16)a[(size_t)(ks * 32 + 8 * lg + j) * NS + col];
            afr[ks] = h;
        }

        f16x4 upf = *(const f16x4*)&u16[(size_t)col * 4];

        __syncthreads();

#pragma unroll 1
        for (int s = 0; s < S_LEN; s++) {
            int cur = s & 1, nxt = cur ^ 1;

            f32x4v acca, accb;
            acca[0] = (float)upf[0]; acca[1] = (float)upf[1];
            acca[2] = (float)upf[2]; acca[3] = (float)upf[3];
            accb = (f32x4v){0.f, 0.f, 0.f, 0.f};

            {
                int sn = (s + 1 < S_LEN) ? s + 1 : S_LEN - 1;
                upf = *(const f16x4*)&u16[((size_t)sn * NS + col) * 4];
            }

            const char* sb = (const char*)Sb + cur * 4352 +
                             (lr & 3) * 1088 + lg * 16;
#pragma unroll
            for (int ks = 0; ks < 16; ks += 2) {
                f16x8 s0 = *(const f16x8*)(sb + ks * 64);
                f16x8 s1 = *(const f16x8*)(sb + ks * 64 + 64);
                acca = MFMA16(s0, afr[ks], acca);
                accb = MFMA16(s1, afr[ks + 1], accb);
            }

            // tanh + publish: X store first (fire-and-forget), then LDS
            if (lg == 0) {
                union { u64 u; f16 h[4]; } pk;
#pragma unroll
                for (int i = 0; i < 4; i++) {
                    float y = acca[i] + accb[i];
                    float e = __expf(2.0f * y);
                    float rc = __builtin_amdgcn_rcpf(e + 1.0f);
                    y = __builtin_fmaf(-2.0f, rc, 1.0f);   // tanh
                    pk.h[i] = (f16)y;
                }
                __hip_atomic_store(&X[(size_t)s * NS + col], pk.u,
                                   __ATOMIC_RELAXED, __HIP_MEMORY_SCOPE_AGENT);
#pragma unroll
                for (int i = 0; i < 4; i++)
                    Sb[nxt * 2176 + i * 544 + col] = pk.h[i];
            }

            if (s == S_LEN - 1) break;

            // data-poll gather: waves 0..5, one remote u64 per lane
            if (w < 6) {
                u64 v;
                do {
                    v = __hip_atomic_load(&X[(size_t)s * NS + gcol],
                                          __ATOMIC_RELAXED,
                                          __HIP_MEMORY_SCOPE_AGENT);
                } while (v == SENT);
                union { u64 u; f16 h[4]; } pk;
                pk.u = v;
#pragma unroll
                for (int i = 0; i < 4; i++)
                    Sb[nxt * 2176 + i * 544 + gcol] = pk.h[i];
            }

            asm volatile("s_waitcnt lgkmcnt(0)" ::: "memory");
            __builtin_amdgcn_s_barrier();
            __builtin_amdgcn_sched_barrier(0);
        }
        return;
    }

    // ================= readout =================
    f16* Ast = (f16*)smem;                 // [256][72]
    f16* Bw = (f16*)(smem + 256 * 72 * 2); // [128][72]

    int idx = bid - NW;
    int bm = idx / 250;      // bm-major: early blocks handle early s
    int bn = idx % 250;
    int s0 = bm * 64;

    if (t == 0) {
        int sc = (bm == 15) ? (S_LEN - 1) : (s0 + 64);
        while (__hip_atomic_load(&X[(size_t)sc * NS], __ATOMIC_RELAXED,
                                 __HIP_MEMORY_SCOPE_AGENT) == SENT)
            __builtin_amdgcn_s_sleep(16);
    }
    __syncthreads();

    int wr = w >> 1, wc = w & 1;

    f32x4v acc[4][4];
#pragma unroll
    for (int i = 0; i < 4; i++)
#pragma unroll
        for (int j = 0; j < 4; j++) acc[i][j] = (f32x4v){0.f, 0.f, 0.f, 0.f};

    for (int kc = 0; kc < 512; kc += 64) {
        __syncthreads();
        // stage A from X: plain (cacheable) loads; agent-scope fallback on
        // sentinel; in-register 4x8 transpose -> 4 ds_write_b128 per thread
        {
            int srel = t >> 3;
            int ck = (t & 7) * 8;
            const u64* xs = &X[(size_t)(s0 + srel) * NS + kc + ck];
            u64 v[8];
#pragma unroll
            for (int j = 0; j < 8; j++) v[j] = xs[j];   // plain, L2-cacheable
#pragma unroll
            for (int j = 0; j < 8; j++)
                while (v[j] == SENT)
                    v[j] = __hip_atomic_load(&xs[j], __ATOMIC_RELAXED,
                                             __HIP_MEMORY_SCOPE_AGENT);
#pragma unroll
            for (int b = 0; b < 4; b++) {
                f16x8 row;
#pragma unroll
                for (int j = 0; j < 8; j++) {
                    union { u64 u; f16 h[4]; } pk;
                    pk.u = v[j];
                    row[j] = pk.h[b];
                }
                *(f16x8*)&Ast[(srel * 4 + b) * 72 + ck] = row;
            }
        }
#pragma unroll
        for (int q = 0; q < 4; q++) {
            int i2 = q * 512 + t;
            int row = i2 >> 4;
            int c0 = (i2 & 15) * 4;
            float4 v = *(const float4*)&cw[(size_t)(bn * 128 + row) * NS + kc + c0];
            f16x4 h;
            h[0] = (f16)v.x; h[1] = (f16)v.y; h[2] = (f16)v.z; h[3] = (f16)v.w;
            *(f16x4*)&Bw[row * 72 + c0] = h;
        }
        __syncthreads();

#pragma unroll
        for (int ks = 0; ks < 2; ks++) {
            f16x8 af[4], bf[4];
#pragma unroll
            for (int mt = 0; mt < 4; mt++)
                af[mt] = *(const f16x8*)&Ast[(wr * 64 + mt * 16 + lr) * 72 +
                                             ks * 32 + 8 * lg];
#pragma unroll
            for (int vt = 0; vt < 4; vt++)
                bf[vt] = *(const f16x8*)&Bw[(wc * 64 + vt * 16 + lr) * 72 +
                                            ks * 32 + 8 * lg];
#pragma unroll
            for (int mt = 0; mt < 4; mt++)
#pragma unroll
                for (int vt = 0; vt < 4; vt++)
                    acc[mt][vt] = MFMA16(af[mt], bf[vt], acc[mt][vt]);
        }
    }

    float bias[4];
#pragma unroll
    for (int vt = 0; vt < 4; vt++)
        bias[vt] = cb[bn * 128 + wc * 64 + vt * 16 + lr];

#pragma unroll
    for (int mt = 0; mt < 4; mt++) {
#pragma unroll
        for (int i = 0; i < 4; i++) {
            int m = bm * 256 + wr * 64 + mt * 16 + 4 * lg + i;
            int bb = m & 3, ss = m >> 2;
            float* orow = out + (size_t)(bb * S_LEN + ss) * NV + bn * 128 + wc * 64;
#pragma unroll
            for (int vt = 0; vt < 4; vt++)
                orow[vt * 16 + lr] = acc[mt][vt][i] + bias[vt];
        }
    }
}

// ---------------------------------------------------------------------------
extern "C" void kernel_launch(void* const* d_in, const int* in_sizes, int n_in,
                              void* d_out, int out_size, void* d_ws, size_t ws_size,
                              hipStream_t stream) {
    (void)in_sizes; (void)n_in; (void)out_size; (void)ws_size;

    const int*   x   = (const int*)d_in[0];
    const float* emb = (const float*)d_in[1];
    const float* a   = (const float*)d_in[2];
    const float* bm  = (const float*)d_in[3];
    const float* cw  = (const float*)d_in[4];
    const float* cb  = (const float*)d_in[5];
    float* out = (float*)d_out;

    char* ws = (char*)d_ws;
    f16* u16 = (f16*)(ws);
    u64* X   = (u64*)(ws + (4u << 20));
    f16* bT16 = (f16*)(ws + (8u << 20));

    hipFuncSetAttribute(reinterpret_cast<const void*>(fused_kernel),
                        hipFuncAttributeMaxDynamicSharedMemorySize,
                        FUSED_LDS);

    transpose512_f16_kernel<<<1024, 256, 0, stream>>>(bm, bT16, X);
    embu_kernel<<<64, 256, 0, stream>>>(x, emb, bT16, u16);
    fused_kernel<<<NW + 16 * 250, 512, FUSED_LDS, stream>>>(
        a, u16, cw, cb, X, out);
}